// Round 19
// baseline (567.366 us; speedup 1.0000x reference)
//
#include <hip/hip_runtime.h>
#include <stdint.h>

// AWQ 4-bit dequant GEMM: out[M,N] = x[M,K] @ W[N,K]^T + bias
// Path 2 (ws >= X+W):
//   prepass x->fp16 row-major (pair-perm + period-4 swizzle, R12-verified)
//   prepass W->fp16 FRAG-MAJOR (1 KB per 16row x 32k frag-tile, R14-verified)
//   GEMM: BM=BN=256, 512 thr (8 waves 2Mx4N, 128x64/wave), 64-k tiles.
//   A: glds->LDS double-buffer (64 KB), staged at tile start for t+1.
//   B: DIRECT global->reg, parity double-buffer (bqA/bqB macros, static
//      names only -- rule #20), refilled for t+2 after compute.
//   Tile end: sched_barrier(0); s_waitcnt vmcnt(8) (FIFO: retires A(t+1) and
//   B(t+1), leaves newly-issued B(t+2)) + s_barrier. Tail: vmcnt(0).
//   Rationale: R12/R13/R18 all pin at 38% MfmaUtil because the LDS pipe
//   (192KB reads + 64KB glds writes ~ 2300-3000cyc/tile) exceeds MFMA
//   (2060cyc). Removing B from LDS drops LDS to ~1500-1900cyc < MFMA.
//   Register budget: 256/wave at 2 waves/SIMD; est 236-246 (R14-16 failed
//   at the 128 budget of 4 waves/SIMD).
// Fallback: reg-staged fused kernel (no ws).

typedef _Float16 f16x2 __attribute__((ext_vector_type(2)));
typedef _Float16 f16x8 __attribute__((ext_vector_type(8)));
typedef float f32x4 __attribute__((ext_vector_type(4)));
typedef unsigned int u32x4 __attribute__((ext_vector_type(4)));

// ---------- prepass: x -> fp16 row-major, pair-perm, period-4 swizzle --------
__global__ void convert_x2_kernel(const float* __restrict__ x,
                                  unsigned short* __restrict__ xh,
                                  int M, int K) {
    int g = blockIdx.x * blockDim.x + threadIdx.x;
    int kc = K >> 3;
    if (g >= M * kc) return;
    int r  = g / kc;
    int cc = g - r * kc;
    int csrc = (cc & ~3) | ((cc & 3) ^ ((r >> 1) & 3));
    const float* p = x + (size_t)r * K + (csrc << 3);
    float4 f0 = *reinterpret_cast<const float4*>(p);
    float4 f1 = *reinterpret_cast<const float4*>(p + 4);
    u32x4 o;
    o.x = __builtin_bit_cast(uint32_t, __builtin_amdgcn_cvt_pkrtz(f0.x, f1.x));
    o.y = __builtin_bit_cast(uint32_t, __builtin_amdgcn_cvt_pkrtz(f0.y, f1.y));
    o.z = __builtin_bit_cast(uint32_t, __builtin_amdgcn_cvt_pkrtz(f0.z, f1.z));
    o.w = __builtin_bit_cast(uint32_t, __builtin_amdgcn_cvt_pkrtz(f0.w, f1.w));
    u32x4* dst = reinterpret_cast<u32x4*>(xh + (size_t)r * K + (cc << 3));
    __builtin_nontemporal_store(o, dst);
}

// ---------- prepass: W int4 -> fp16 FRAG-MAJOR dequant (R14-verified) --------
// dest chunk d (16B): l=d&63, kt=(d>>6)%(K/32), gg=(d>>6)/(K/32)
// source row o=gg*16+(l&15), dword qw[o][kt*4 + (l>>4)]; pair-permuted chunk.
__global__ void convert_w3_kernel(const int* __restrict__ qw,
                                  const int* __restrict__ qz,
                                  const float* __restrict__ sc,
                                  unsigned short* __restrict__ whf,
                                  int Nrows, int K) {
    int d = blockIdx.x * blockDim.x + threadIdx.x;
    int kt32 = K >> 5;
    int total = Nrows * (K >> 3);
    if (d >= total) return;
    int l   = d & 63;
    int rest = d >> 6;
    int kt  = rest % kt32;
    int gg  = rest / kt32;
    int o   = gg * 16 + (l & 15);
    int c   = l >> 4;
    int ngrp = K >> 7, nzw = ngrp >> 3;
    int grp = kt >> 2;
    float s = sc[(size_t)o * ngrp + grp];
    uint32_t z = ((uint32_t)qz[(size_t)o * nzw + (grp >> 3)] >> ((grp & 7) << 2)) & 0xF;
    uint32_t u = (uint32_t)qw[(size_t)o * (K >> 3) + kt * 4 + c];
    _Float16 hs = (_Float16)s;
    _Float16 hz = (_Float16)(1024.0f + (float)z);   // integer <=1039: exact fp16
    f16x2 s2 = {hs, hs}, z2 = {hz, hz};
    const uint32_t MK = 0x000F000Fu, MG = 0x64006400u;
    uint32_t p0 = (u & MK) | MG;
    uint32_t p1 = ((u >> 4) & MK) | MG;
    uint32_t p2 = ((u >> 8) & MK) | MG;
    uint32_t p3 = ((u >> 12) & MK) | MG;
    u32x4 ov;
    ov.x = __builtin_bit_cast(uint32_t, (__builtin_bit_cast(f16x2, p0) - z2) * s2);
    ov.y = __builtin_bit_cast(uint32_t, (__builtin_bit_cast(f16x2, p1) - z2) * s2);
    ov.z = __builtin_bit_cast(uint32_t, (__builtin_bit_cast(f16x2, p2) - z2) * s2);
    ov.w = __builtin_bit_cast(uint32_t, (__builtin_bit_cast(f16x2, p3) - z2) * s2);
    __builtin_nontemporal_store(ov, reinterpret_cast<u32x4*>(whf + (size_t)d * 8));
}

// ---------- path 2 GEMM: A via LDS (64 KB dbuf), B direct-to-reg -------------
__global__ __launch_bounds__(512, 2) void awq_gemmbr_kernel(
    const unsigned short* __restrict__ xh,
    const unsigned short* __restrict__ whf,
    const float* __restrict__ bias,
    float* __restrict__ out,
    int M, int N, int K)
{
    extern __shared__ __align__(16) unsigned short lds[];
    const int TSZ = 256 * 32;                 // 8192 u16 = 16 KB per A subtile
    unsigned short* AB = lds;                 // [2 buf][2 sub][TSZ] = 64 KB

    const int tid  = threadIdx.x;
    const int lane = tid & 63;
    const int wave = tid >> 6;
    const int wr   = wave >> 2;               // 0..1: 128-row half of A
    const int wc   = wave & 3;                // 0..3: 64-col quarter of B
    const int lrow = lane & 15;
    const int cswz = (((lane >> 4) ^ ((lrow >> 1) & 3)) << 3);  // elems

    const int cpx = gridDim.x >> 3;
    const int bid = (blockIdx.x & 7) * cpx + (blockIdx.x >> 3);
    const int ntn = N / 256;                  // 16
    const int m0 = (bid / ntn) * 256;
    const int n0 = (bid % ntn) * 256;
    const int NT = K >> 6;                    // 64 tiles of 64 k
    const int kt32 = K >> 5;

    f32x4 acc[8][4];
    #pragma unroll
    for (int m = 0; m < 8; ++m)
        #pragma unroll
        for (int n = 0; n < 4; ++n)
            #pragma unroll
            for (int e = 0; e < 4; ++e) acc[m][n][e] = 0.f;

    // B frag-major base: group g = n0/16 + wc*4 + n
    const unsigned short* bb0 = whf + ((size_t)((n0 >> 4) + wc * 4) * kt32) * 512 + lane * 8;
    const size_t bstride = (size_t)kt32 * 512;

    // stage one 256x32 A subtile: 2 glds per thread (R12/R18-verified map)
    auto GLDS = [&](int kt, unsigned short* dst) {
        #pragma unroll
        for (int i = 0; i < 2; ++i) {
            int row = wave * 32 + i * 16 + (lane >> 2);
            const unsigned short* g = xh + (size_t)(m0 + row) * K + kt + ((lane & 3) << 3);
            unsigned short* d = dst + row * 32 + ((lane & 3) << 3);
            __builtin_amdgcn_global_load_lds(
                (const __attribute__((address_space(1))) unsigned int*)g,
                (__attribute__((address_space(3))) unsigned int*)d, 16, 0, 0);
        }
    };
    // stage A 64-k tile t into buffer b (4 glds instr/wave)
    auto STAGE_A = [&](int t, int b) {
        GLDS(t * 64,      AB + (b * 2 + 0) * TSZ);
        GLDS(t * 64 + 32, AB + (b * 2 + 1) * TSZ);
    };

    uint4 bqA[8], bqB[8];   // [n*2+sub]; ONLY touched via static-name macros

#define LOADB_TO(bq, t2)                                                      \
    _Pragma("unroll")                                                         \
    for (int n_ = 0; n_ < 4; ++n_)                                            \
        _Pragma("unroll")                                                     \
        for (int s_ = 0; s_ < 2; ++s_)                                        \
            bq[n_ * 2 + s_] = *reinterpret_cast<const uint4*>(                \
                bb0 + n_ * bstride + (size_t)(2 * (t2) + s_) * 512);

#define TILE_M(t, bq)                                                         \
    {                                                                         \
        const int rb_ = (t) & 1;                                              \
        if ((t) + 1 < NT) STAGE_A((t) + 1, rb_ ^ 1);                          \
        _Pragma("unroll")                                                     \
        for (int s_ = 0; s_ < 2; ++s_) {                                      \
            const unsigned short* Ab_ = AB + (rb_ * 2 + s_) * TSZ;            \
            f16x8 bf0_ = __builtin_bit_cast(f16x8, bq[0 * 2 + s_]);           \
            f16x8 bf1_ = __builtin_bit_cast(f16x8, bq[1 * 2 + s_]);           \
            f16x8 bf2_ = __builtin_bit_cast(f16x8, bq[2 * 2 + s_]);           \
            f16x8 bf3_ = __builtin_bit_cast(f16x8, bq[3 * 2 + s_]);           \
            _Pragma("unroll")                                                 \
            for (int m_ = 0; m_ < 8; ++m_) {                                  \
                int row_ = wr * 128 + m_ * 16 + lrow;                         \
                f16x8 a_ = __builtin_bit_cast(f16x8,                          \
                    *reinterpret_cast<const uint4*>(&Ab_[row_ * 32 + cswz])); \
                acc[m_][0] = __builtin_amdgcn_mfma_f32_16x16x32_f16(          \
                    a_, bf0_, acc[m_][0], 0, 0, 0);                           \
                acc[m_][1] = __builtin_amdgcn_mfma_f32_16x16x32_f16(          \
                    a_, bf1_, acc[m_][1], 0, 0, 0);                           \
                acc[m_][2] = __builtin_amdgcn_mfma_f32_16x16x32_f16(          \
                    a_, bf2_, acc[m_][2], 0, 0, 0);                           \
                acc[m_][3] = __builtin_amdgcn_mfma_f32_16x16x32_f16(          \
                    a_, bf3_, acc[m_][3], 0, 0, 0);                           \
            }                                                                 \
        }                                                                     \
        __builtin_amdgcn_sched_barrier(0);                                    \
        if ((t) + 2 < NT) {                                                   \
            LOADB_TO(bq, (t) + 2)                                             \
            asm volatile("s_waitcnt vmcnt(8)" ::: "memory");                  \
        } else {                                                              \
            asm volatile("s_waitcnt vmcnt(0)" ::: "memory");                  \
        }                                                                     \
        __builtin_amdgcn_s_barrier();                                         \
    }

    // ---- prologue: B(0)->bqA, B(1)->bqB; A tile 0 -> buf 0; drain; barrier
    LOADB_TO(bqA, 0)
    LOADB_TO(bqB, 1)
    STAGE_A(0, 0);
    asm volatile("s_waitcnt vmcnt(0)" ::: "memory");
    __syncthreads();

    for (int t = 0; t < NT; t += 2) {
        TILE_M(t, bqA)
        TILE_M(t + 1, bqB)
    }
#undef TILE_M
#undef LOADB_TO

    // epilogue: C frag col=lane&15, row=(lane>>4)*4+e
    const int r4 = (lane >> 4) << 2;
    #pragma unroll
    for (int n = 0; n < 4; ++n) {
        int col = n0 + wc * 64 + n * 16 + lrow;
        float bv = bias[col];
        #pragma unroll
        for (int m = 0; m < 8; ++m) {
            size_t rbase = (size_t)(m0 + wr * 128 + m * 16 + r4) * N + col;
            #pragma unroll
            for (int e = 0; e < 4; ++e)
                __builtin_nontemporal_store(acc[m][n][e] + bv, &out[rbase + (size_t)e * N]);
        }
    }
}

// ================= fallback (ws too small): reg-staged fused ================
#define BM 256
#define BN 256
#define BK 64

__global__ __launch_bounds__(512, 2) void awq_gemm0_kernel(
    const float* __restrict__ x,
    const int*   __restrict__ qw,
    const int*   __restrict__ qz,
    const float* __restrict__ sc,
    const float* __restrict__ bias,
    float*       __restrict__ out,
    int M, int N, int K)
{
    extern __shared__ __align__(16) unsigned short lds[];
    const int ASZ  = BM * BK;
    const int BPSZ = BN * (BK / 8);
    unsigned short* As = lds;
    uint32_t* Bp = reinterpret_cast<uint32_t*>(lds + 2 * ASZ);

    const int tid  = threadIdx.x;
    const int lane = tid & 63;
    const int wave = tid >> 6;
    const int wr   = wave >> 2;
    const int wc   = wave & 3;
    const int lrow = lane & 15;
    const int lko  = (lane >> 4) << 3;
    const int swr  = (lrow & 7) << 3;

    const int cpx = gridDim.x >> 3;
    const int bid = (blockIdx.x & 7) * cpx + (blockIdx.x >> 3);
    const int ntn = N / BN;
    const int m0 = (bid / ntn) * BM;
    const int n0 = (bid % ntn) * BN;

    const int ngrp = K >> 7;
    const int nzw  = ngrp >> 3;
    const int kw   = K >> 3;
    const int NT   = K / BK;

    const int r_s = tid >> 1;
    const int kh  = tid & 1;
    const int sws = (r_s & 7) << 3;

    f32x4 acc[8][4];
    #pragma unroll
    for (int m = 0; m < 8; ++m)
        #pragma unroll
        for (int n = 0; n < 4; ++n)
            #pragma unroll
            for (int e = 0; e < 4; ++e) acc[m][n][e] = 0.f;

    float    sc_pf[4];
    uint32_t zq_pf[4];
    f16x2    ss[4], zz[4];
    auto PFG = [&](int grp) {
        #pragma unroll
        for (int n = 0; n < 4; ++n) {
            int og = n0 + wc * 64 + n * 16 + lrow;
            sc_pf[n] = sc[(size_t)og * ngrp + grp];
            zq_pf[n] = (uint32_t)qz[(size_t)og * nzw + (grp >> 3)];
        }
    };
    auto SETG = [&](int grp) {
        #pragma unroll
        for (int n = 0; n < 4; ++n) {
            _Float16 s = (_Float16)sc_pf[n];
            uint32_t z = (zq_pf[n] >> ((grp & 7) << 2)) & 0xF;
            _Float16 Z = (_Float16)(float)(1024u + z);
            ss[n][0] = s; ss[n][1] = s;
            zz[n][0] = Z; zz[n][1] = Z;
        }
    };

    float4 a32[8];

    auto GLDSB = [&](int kt, uint32_t* Bw) {
        int row = tid >> 1;
        const int* g = qw + (size_t)(n0 + row) * kw + (kt >> 3) + (tid & 1) * 4;
        uint32_t* d = Bw + row * 8 + (tid & 1) * 4;
        __builtin_amdgcn_global_load_lds(
            (const __attribute__((address_space(1))) unsigned int*)g,
            (__attribute__((address_space(3))) unsigned int*)d, 16, 0, 0);
    };
    auto LOADA = [&](int kt) {
        const float* p = x + (size_t)(m0 + r_s) * K + kt + kh * 32;
        #pragma unroll
        for (int i = 0; i < 8; ++i)
            a32[i] = *reinterpret_cast<const float4*>(p + 4 * i);
    };
    auto WA = [&](unsigned short* dst, int c) {
        uint4 o;
        o.x = __builtin_bit_cast(uint32_t, __builtin_amdgcn_cvt_pkrtz(a32[2*c].x, a32[2*c+1].x));
        o.y = __builtin_bit_cast(uint32_t, __builtin_amdgcn_cvt_pkrtz(a32[2*c].y, a32[2*c+1].y));
        o.z = __builtin_bit_cast(uint32_t, __builtin_amdgcn_cvt_pkrtz(a32[2*c].z, a32[2*c+1].z));
        o.w = __builtin_bit_cast(uint32_t, __builtin_amdgcn_cvt_pkrtz(a32[2*c].w, a32[2*c+1].w));
        int kcol = kh * 32 + 8 * c;
        *reinterpret_cast<uint4*>(&dst[r_s * BK + (kcol ^ sws)]) = o;
    };

    f16x8 af[4], bfA[4], bfB[4];
    auto RDA = [&](const unsigned short* Ab, int mh, int kk) {
        #pragma unroll
        for (int m = 0; m < 4; ++m) {
            int arow = wr * 128 + (mh * 4 + m) * 16 + lrow;
            int idx = arow * BK + ((kk * 32 + lko) ^ swr);
            af[m] = __builtin_bit_cast(f16x8, *reinterpret_cast<const uint4*>(&Ab[idx]));
        }
    };
    auto DEQB = [&](const uint32_t* Bpb, f16x8* b, int kk) {
        const int dcol = kk * 4 + (lane >> 4);
        const uint32_t MK = 0x000F000Fu, MG = 0x64006400u;
        #pragma unroll
        for (int n = 0; n < 4; ++n) {
            int brow = wc * 64 + n * 16 + lrow;
            uint32_t u = Bpb[brow * 8 + dcol];
            uint32_t p0 = (u & MK) | MG;
            uint32_t p1 = ((u >> 4) & MK) | MG;
            uint32_t p2 = ((u >> 8) & MK) | MG;
            uint32_t p3 = ((u >> 12) & MK) | MG;
            u32x4 o;
            o.x = __builtin_bit_cast(uint32_t, (__builtin_bit_cast(f16x2, p0) - zz[n]) * ss[n]);
            o.y = __builtin_bit_cast(uint32_t, (__builtin_bit_cast(f16x2, p1) - zz[n]) * ss[n]);
            o.z = __builtin_bit_cast(uint32_t, (__builtin_bit_cast(f16x2, p2) - zz[n]) * ss[n]);
            o.w = __builtin_bit_cast(uint32_t, (__builtin_bit_cast(f16x2, p3) - zz[n]) * ss[n]);
            b[n] = __builtin_bit_cast(f16x8, o);
        }
    };
    auto MFMAQ = [&](f16x8* bf, int mh) {
        #pragma unroll
        for (int m_ = 0; m_ < 4; ++m_)
            #pragma unroll
            for (int n_ = 0; n_ < 4; ++n_)
                acc[mh * 4 + m_][n_] = __builtin_amdgcn_mfma_f32_16x16x32_f16(
                    af[m_], bf[n_], acc[mh * 4 + m_][n_], 0, 0, 0);
    };

    PFG(0);
    GLDSB(0, Bp);
    LOADA(0);
    asm volatile("s_waitcnt vmcnt(0)" ::: "memory");
    #pragma unroll
    for (int c = 0; c < 4; ++c) WA(As, c);
    SETG(0);
    __syncthreads();

    for (int t = 0; t < NT; ++t) {
        const int grp = t >> 1;
        if (t && !(t & 1)) SETG(grp);
        if ((t & 1) && grp + 1 < ngrp) PFG(grp + 1);

        const int buf = t & 1;
        const unsigned short* Ab = As + buf * ASZ;
        const uint32_t* Bpb = Bp + buf * BPSZ;
        if (t + 1 < NT) {
            GLDSB((t + 1) * BK, Bp + (buf ^ 1) * BPSZ);
            LOADA((t + 1) * BK);
        }

        DEQB(Bpb, bfA, 0);
        RDA(Ab, 0, 0);
        MFMAQ(bfA, 0);
        RDA(Ab, 1, 0);
        MFMAQ(bfA, 1);
        DEQB(Bpb, bfB, 1);
        RDA(Ab, 0, 1);
        MFMAQ(bfB, 0);
        RDA(Ab, 1, 1);
        MFMAQ(bfB, 1);

        if (t + 1 < NT) { WA(As + (buf ^ 1) * ASZ, 0); WA(As + (buf ^ 1) * ASZ, 1);
                          WA(As + (buf ^ 1) * ASZ, 2); WA(As + (buf ^ 1) * ASZ, 3); }
        __syncthreads();
    }

    const int r4 = (lane >> 4) << 2;
    #pragma unroll
    for (int n = 0; n < 4; ++n) {
        int col = n0 + wc * 64 + n * 16 + lrow;
        float bv = bias[col];
        #pragma unroll
        for (int m = 0; m < 8; ++m) {
            size_t rbase = (size_t)(m0 + wr * 128 + m * 16 + r4) * N + col;
            #pragma unroll
            for (int e = 0; e < 4; ++e)
                __builtin_nontemporal_store(acc[m][n][e] + bv, &out[rbase + (size_t)e * N]);
        }
    }
}

extern "C" void kernel_launch(void* const* d_in, const int* in_sizes, int n_in,
                              void* d_out, int out_size, void* d_ws, size_t ws_size,
                              hipStream_t stream) {
    const float* x   = (const float*)d_in[0];
    const int*   qwp = (const int*)d_in[1];
    const int*   qzp = (const int*)d_in[2];
    const float* scp = (const float*)d_in[3];
    const float* bp  = (const float*)d_in[4];
    float* outp = (float*)d_out;

    const int N = in_sizes[4];                 // 4096 (O)
    const int K = (in_sizes[1] / N) * 8;       // 4096 (I)
    const int M = in_sizes[0] / K;             // 8192 (B)

    dim3 block(512);
    const size_t needX = (size_t)M * K * 2;
    const size_t needW = (size_t)N * K * 2;

    if (ws_size >= needX + needW) {
        unsigned short* xh  = (unsigned short*)d_ws;
        unsigned short* whf = xh + (size_t)M * K;
        int ncx = M * (K / 8), ncw = N * (K / 8);
        convert_x2_kernel<<<dim3((ncx + 255) / 256), dim3(256), 0, stream>>>(x, xh, M, K);
        convert_w3_kernel<<<dim3((ncw + 255) / 256), dim3(256), 0, stream>>>(qwp, qzp, scp, whf, N, K);
        dim3 grid2((M / 256) * (N / 256));     // 32*16 = 512
        const int ldsbytes = 4 * 256 * 32 * 2; // 64 KB (A only)
        (void)hipFuncSetAttribute(
            reinterpret_cast<const void*>(&awq_gemmbr_kernel),
            hipFuncAttributeMaxDynamicSharedMemorySize, ldsbytes);
        awq_gemmbr_kernel<<<grid2, block, ldsbytes, stream>>>(xh, whf, bp, outp, M, N, K);
    } else {
        dim3 grid((M / BM) * (N / BN));
        const int ldsbytes = 2 * BM * BK * 2 + 2 * BN * (BK / 8) * 4;
        (void)hipFuncSetAttribute(
            reinterpret_cast<const void*>(&awq_gemm0_kernel),
            hipFuncAttributeMaxDynamicSharedMemorySize, ldsbytes);
        awq_gemm0_kernel<<<grid, block, ldsbytes, stream>>>(
            x, qwp, qzp, scp, bp, outp, M, N, K);
    }
}

// Round 20
// 352.727 us; speedup vs baseline: 1.6085x; 1.6085x over previous
//
#include <hip/hip_runtime.h>
#include <stdint.h>

// AWQ 4-bit dequant GEMM: out[M,N] = x[M,K] @ W[N,K]^T + bias
// Path 2 (ws >= X+W):
//   prepass x->fp16 row-major (pair-perm + period-4 swizzle, R12-verified)
//   prepass W->fp16 FRAG-MAJOR (1 KB per 16row x 32k frag-tile, R14-verified)
//   GEMM: BM=BN=256, 512 thr (8 waves 2Mx4N, 128x64/wave), 64-k tiles.
//   A: glds->LDS double-buffer (64 KB), staged at tile start for t+1.
//   B: DIRECT global->reg, ONE 16-reg set per subtile (bq0/bq1, static macro
//      names -- rule #20), refilled immediately AFTER last use (~1900 cyc
//      cover). Tile end: s_waitcnt vmcnt(4) (FIFO: retires A(t+1)+bq0,
//      leaves 4 newest bq1 loads) + s_barrier; compiler reg-dep waits cover
//      bq1's next-tile use. Tail: vmcnt(0).
//   Mechanism (R12/R18/R19 ledger): 38% MfmaUtil wall = LDS instr throughput
//   (256 KB/tile / 85 B/cyc ~ 3000 cyc vs MFMA wall 1030). B out of LDS ->
//   160 KB ~ 1900 cyc -> ceiling ~54%. R19 spilled (64 B-regs, ~10 headroom);
//   this uses 32 B-regs, ~50 headroom.
// Fallback: reg-staged fused kernel (no ws).

typedef _Float16 f16x2 __attribute__((ext_vector_type(2)));
typedef _Float16 f16x8 __attribute__((ext_vector_type(8)));
typedef float f32x4 __attribute__((ext_vector_type(4)));
typedef unsigned int u32x4 __attribute__((ext_vector_type(4)));

// ---------- prepass: x -> fp16 row-major, pair-perm, period-4 swizzle --------
__global__ void convert_x2_kernel(const float* __restrict__ x,
                                  unsigned short* __restrict__ xh,
                                  int M, int K) {
    int g = blockIdx.x * blockDim.x + threadIdx.x;
    int kc = K >> 3;
    if (g >= M * kc) return;
    int r  = g / kc;
    int cc = g - r * kc;
    int csrc = (cc & ~3) | ((cc & 3) ^ ((r >> 1) & 3));
    const float* p = x + (size_t)r * K + (csrc << 3);
    float4 f0 = *reinterpret_cast<const float4*>(p);
    float4 f1 = *reinterpret_cast<const float4*>(p + 4);
    u32x4 o;
    o.x = __builtin_bit_cast(uint32_t, __builtin_amdgcn_cvt_pkrtz(f0.x, f1.x));
    o.y = __builtin_bit_cast(uint32_t, __builtin_amdgcn_cvt_pkrtz(f0.y, f1.y));
    o.z = __builtin_bit_cast(uint32_t, __builtin_amdgcn_cvt_pkrtz(f0.z, f1.z));
    o.w = __builtin_bit_cast(uint32_t, __builtin_amdgcn_cvt_pkrtz(f0.w, f1.w));
    u32x4* dst = reinterpret_cast<u32x4*>(xh + (size_t)r * K + (cc << 3));
    __builtin_nontemporal_store(o, dst);
}

// ---------- prepass: W int4 -> fp16 FRAG-MAJOR dequant (R14-verified) --------
__global__ void convert_w3_kernel(const int* __restrict__ qw,
                                  const int* __restrict__ qz,
                                  const float* __restrict__ sc,
                                  unsigned short* __restrict__ whf,
                                  int Nrows, int K) {
    int d = blockIdx.x * blockDim.x + threadIdx.x;
    int kt32 = K >> 5;
    int total = Nrows * (K >> 3);
    if (d >= total) return;
    int l   = d & 63;
    int rest = d >> 6;
    int kt  = rest % kt32;
    int gg  = rest / kt32;
    int o   = gg * 16 + (l & 15);
    int c   = l >> 4;
    int ngrp = K >> 7, nzw = ngrp >> 3;
    int grp = kt >> 2;
    float s = sc[(size_t)o * ngrp + grp];
    uint32_t z = ((uint32_t)qz[(size_t)o * nzw + (grp >> 3)] >> ((grp & 7) << 2)) & 0xF;
    uint32_t u = (uint32_t)qw[(size_t)o * (K >> 3) + kt * 4 + c];
    _Float16 hs = (_Float16)s;
    _Float16 hz = (_Float16)(1024.0f + (float)z);   // integer <=1039: exact fp16
    f16x2 s2 = {hs, hs}, z2 = {hz, hz};
    const uint32_t MK = 0x000F000Fu, MG = 0x64006400u;
    uint32_t p0 = (u & MK) | MG;
    uint32_t p1 = ((u >> 4) & MK) | MG;
    uint32_t p2 = ((u >> 8) & MK) | MG;
    uint32_t p3 = ((u >> 12) & MK) | MG;
    u32x4 ov;
    ov.x = __builtin_bit_cast(uint32_t, (__builtin_bit_cast(f16x2, p0) - z2) * s2);
    ov.y = __builtin_bit_cast(uint32_t, (__builtin_bit_cast(f16x2, p1) - z2) * s2);
    ov.z = __builtin_bit_cast(uint32_t, (__builtin_bit_cast(f16x2, p2) - z2) * s2);
    ov.w = __builtin_bit_cast(uint32_t, (__builtin_bit_cast(f16x2, p3) - z2) * s2);
    __builtin_nontemporal_store(ov, reinterpret_cast<u32x4*>(whf + (size_t)d * 8));
}

// ---------- path 2 GEMM: A via LDS (64 KB dbuf), B direct-to-reg (2x16 regs) -
__global__ __launch_bounds__(512, 2) void awq_gemmbr_kernel(
    const unsigned short* __restrict__ xh,
    const unsigned short* __restrict__ whf,
    const float* __restrict__ bias,
    float* __restrict__ out,
    int M, int N, int K)
{
    extern __shared__ __align__(16) unsigned short lds[];
    const int TSZ = 256 * 32;                 // 8192 u16 = 16 KB per A subtile
    unsigned short* AB = lds;                 // [2 buf][2 sub][TSZ] = 64 KB

    const int tid  = threadIdx.x;
    const int lane = tid & 63;
    const int wave = tid >> 6;
    const int wr   = wave >> 2;               // 0..1: 128-row half of A
    const int wc   = wave & 3;                // 0..3: 64-col quarter of B
    const int lrow = lane & 15;
    const int cswz = (((lane >> 4) ^ ((lrow >> 1) & 3)) << 3);  // elems

    const int cpx = gridDim.x >> 3;
    const int bid = (blockIdx.x & 7) * cpx + (blockIdx.x >> 3);
    const int ntn = N / 256;                  // 16
    const int m0 = (bid / ntn) * 256;
    const int n0 = (bid % ntn) * 256;
    const int NT = K >> 6;                    // 64 tiles of 64 k
    const int kt32 = K >> 5;

    f32x4 acc[8][4];
    #pragma unroll
    for (int m = 0; m < 8; ++m)
        #pragma unroll
        for (int n = 0; n < 4; ++n)
            #pragma unroll
            for (int e = 0; e < 4; ++e) acc[m][n][e] = 0.f;

    // B frag-major base: group g = n0/16 + wc*4 + n (R14-verified addressing)
    const unsigned short* bb0 = whf + ((size_t)((n0 >> 4) + wc * 4) * kt32) * 512 + lane * 8;
    const size_t bstride = (size_t)kt32 * 512;

    // stage one 256x32 A subtile: 2 glds per thread (R12/R18-verified map)
    auto GLDS = [&](int kt, unsigned short* dst) {
        #pragma unroll
        for (int i = 0; i < 2; ++i) {
            int row = wave * 32 + i * 16 + (lane >> 2);
            const unsigned short* g = xh + (size_t)(m0 + row) * K + kt + ((lane & 3) << 3);
            unsigned short* d = dst + row * 32 + ((lane & 3) << 3);
            __builtin_amdgcn_global_load_lds(
                (const __attribute__((address_space(1))) unsigned int*)g,
                (__attribute__((address_space(3))) unsigned int*)d, 16, 0, 0);
        }
    };
    // stage A 64-k tile t into buffer b (4 glds instr/wave)
    auto STAGE_A = [&](int t, int b) {
        GLDS(t * 64,      AB + (b * 2 + 0) * TSZ);
        GLDS(t * 64 + 32, AB + (b * 2 + 1) * TSZ);
    };

    uint4 bq0[4], bq1[4];   // one 32-k subtile of B each; static-name access only

// load B k-subtile st (global index, 32-k units) into named array
#define LOADB(bq, st)                                                         \
    _Pragma("unroll")                                                         \
    for (int n_ = 0; n_ < 4; ++n_)                                            \
        bq[n_] = *reinterpret_cast<const uint4*>(                             \
            bb0 + n_ * bstride + (size_t)(st) * 512);

// 32 MFMAs of one subtile: A from LDS (streamed singly), B from named regs
#define MFMASUB(sub, bq)                                                      \
    {                                                                         \
        const unsigned short* Ab_ = AB + (buf * 2 + (sub)) * TSZ;             \
        f16x8 b0_ = __builtin_bit_cast(f16x8, bq[0]);                         \
        f16x8 b1_ = __builtin_bit_cast(f16x8, bq[1]);                         \
        f16x8 b2_ = __builtin_bit_cast(f16x8, bq[2]);                         \
        f16x8 b3_ = __builtin_bit_cast(f16x8, bq[3]);                         \
        _Pragma("unroll")                                                     \
        for (int m_ = 0; m_ < 8; ++m_) {                                      \
            int row_ = wr * 128 + m_ * 16 + lrow;                             \
            f16x8 a_ = __builtin_bit_cast(f16x8,                              \
                *reinterpret_cast<const uint4*>(&Ab_[row_ * 32 + cswz]));     \
            acc[m_][0] = __builtin_amdgcn_mfma_f32_16x16x32_f16(              \
                a_, b0_, acc[m_][0], 0, 0, 0);                                \
            acc[m_][1] = __builtin_amdgcn_mfma_f32_16x16x32_f16(              \
                a_, b1_, acc[m_][1], 0, 0, 0);                                \
            acc[m_][2] = __builtin_amdgcn_mfma_f32_16x16x32_f16(              \
                a_, b2_, acc[m_][2], 0, 0, 0);                                \
            acc[m_][3] = __builtin_amdgcn_mfma_f32_16x16x32_f16(              \
                a_, b3_, acc[m_][3], 0, 0, 0);                                \
        }                                                                     \
    }

    // ---- prologue: bq0<-sub(0), bq1<-sub(1); A tile 0 -> buf 0; drain; bar
    LOADB(bq0, 0)
    LOADB(bq1, 1)
    STAGE_A(0, 0);
    asm volatile("s_waitcnt vmcnt(0)" ::: "memory");
    __syncthreads();

    for (int t = 0; t < NT; ++t) {
        const int buf = t & 1;
        const bool pf = (t + 1 < NT);
        // A(t+1) glds first: full tile (~2500 cyc) to land
        if (pf) STAGE_A(t + 1, buf ^ 1);

        // subtile 0: consume bq0, then refill it for t+1 (distance ~1 subtile
        // + barrier + next tile's sub0 lead-in)
        MFMASUB(0, bq0)
        if (pf) { LOADB(bq0, 2 * (t + 1)) }

        // subtile 1: consume bq1, then refill for t+1 (consumed mid-next-tile;
        // compiler reg-dep wait covers the remainder)
        MFMASUB(1, bq1)
        if (pf) { LOADB(bq1, 2 * (t + 1) + 1) }

        // tile end: counted wait. Newest 4 outstanding = bq1 refill; all older
        // (A(t+1) glds, bq0 refill) retired -> A buf^1 safe to read after bar.
        if (pf) { asm volatile("s_waitcnt vmcnt(4)" ::: "memory"); }
        else    { asm volatile("s_waitcnt vmcnt(0)" ::: "memory"); }
        __builtin_amdgcn_s_barrier();
    }
#undef MFMASUB
#undef LOADB

    // epilogue: C frag col=lane&15, row=(lane>>4)*4+e
    const int r4 = (lane >> 4) << 2;
    #pragma unroll
    for (int n = 0; n < 4; ++n) {
        int col = n0 + wc * 64 + n * 16 + lrow;
        float bv = bias[col];
        #pragma unroll
        for (int m = 0; m < 8; ++m) {
            size_t rbase = (size_t)(m0 + wr * 128 + m * 16 + r4) * N + col;
            #pragma unroll
            for (int e = 0; e < 4; ++e)
                __builtin_nontemporal_store(acc[m][n][e] + bv, &out[rbase + (size_t)e * N]);
        }
    }
}

// ================= fallback (ws too small): reg-staged fused ================
#define BM 256
#define BN 256
#define BK 64

__global__ __launch_bounds__(512, 2) void awq_gemm0_kernel(
    const float* __restrict__ x,
    const int*   __restrict__ qw,
    const int*   __restrict__ qz,
    const float* __restrict__ sc,
    const float* __restrict__ bias,
    float*       __restrict__ out,
    int M, int N, int K)
{
    extern __shared__ __align__(16) unsigned short lds[];
    const int ASZ  = BM * BK;
    const int BPSZ = BN * (BK / 8);
    unsigned short* As = lds;
    uint32_t* Bp = reinterpret_cast<uint32_t*>(lds + 2 * ASZ);

    const int tid  = threadIdx.x;
    const int lane = tid & 63;
    const int wave = tid >> 6;
    const int wr   = wave >> 2;
    const int wc   = wave & 3;
    const int lrow = lane & 15;
    const int lko  = (lane >> 4) << 3;
    const int swr  = (lrow & 7) << 3;

    const int cpx = gridDim.x >> 3;
    const int bid = (blockIdx.x & 7) * cpx + (blockIdx.x >> 3);
    const int ntn = N / BN;
    const int m0 = (bid / ntn) * BM;
    const int n0 = (bid % ntn) * BN;

    const int ngrp = K >> 7;
    const int nzw  = ngrp >> 3;
    const int kw   = K >> 3;
    const int NT   = K / BK;

    const int r_s = tid >> 1;
    const int kh  = tid & 1;
    const int sws = (r_s & 7) << 3;

    f32x4 acc[8][4];
    #pragma unroll
    for (int m = 0; m < 8; ++m)
        #pragma unroll
        for (int n = 0; n < 4; ++n)
            #pragma unroll
            for (int e = 0; e < 4; ++e) acc[m][n][e] = 0.f;

    float    sc_pf[4];
    uint32_t zq_pf[4];
    f16x2    ss[4], zz[4];
    auto PFG = [&](int grp) {
        #pragma unroll
        for (int n = 0; n < 4; ++n) {
            int og = n0 + wc * 64 + n * 16 + lrow;
            sc_pf[n] = sc[(size_t)og * ngrp + grp];
            zq_pf[n] = (uint32_t)qz[(size_t)og * nzw + (grp >> 3)];
        }
    };
    auto SETG = [&](int grp) {
        #pragma unroll
        for (int n = 0; n < 4; ++n) {
            _Float16 s = (_Float16)sc_pf[n];
            uint32_t z = (zq_pf[n] >> ((grp & 7) << 2)) & 0xF;
            _Float16 Z = (_Float16)(float)(1024u + z);
            ss[n][0] = s; ss[n][1] = s;
            zz[n][0] = Z; zz[n][1] = Z;
        }
    };

    float4 a32[8];

    auto GLDSB = [&](int kt, uint32_t* Bw) {
        int row = tid >> 1;
        const int* g = qw + (size_t)(n0 + row) * kw + (kt >> 3) + (tid & 1) * 4;
        uint32_t* d = Bw + row * 8 + (tid & 1) * 4;
        __builtin_amdgcn_global_load_lds(
            (const __attribute__((address_space(1))) unsigned int*)g,
            (__attribute__((address_space(3))) unsigned int*)d, 16, 0, 0);
    };
    auto LOADA = [&](int kt) {
        const float* p = x + (size_t)(m0 + r_s) * K + kt + kh * 32;
        #pragma unroll
        for (int i = 0; i < 8; ++i)
            a32[i] = *reinterpret_cast<const float4*>(p + 4 * i);
    };
    auto WA = [&](unsigned short* dst, int c) {
        uint4 o;
        o.x = __builtin_bit_cast(uint32_t, __builtin_amdgcn_cvt_pkrtz(a32[2*c].x, a32[2*c+1].x));
        o.y = __builtin_bit_cast(uint32_t, __builtin_amdgcn_cvt_pkrtz(a32[2*c].y, a32[2*c+1].y));
        o.z = __builtin_bit_cast(uint32_t, __builtin_amdgcn_cvt_pkrtz(a32[2*c].z, a32[2*c+1].z));
        o.w = __builtin_bit_cast(uint32_t, __builtin_amdgcn_cvt_pkrtz(a32[2*c].w, a32[2*c+1].w));
        int kcol = kh * 32 + 8 * c;
        *reinterpret_cast<uint4*>(&dst[r_s * BK + (kcol ^ sws)]) = o;
    };

    f16x8 af[4], bfA[4], bfB[4];
    auto RDA = [&](const unsigned short* Ab, int mh, int kk) {
        #pragma unroll
        for (int m = 0; m < 4; ++m) {
            int arow = wr * 128 + (mh * 4 + m) * 16 + lrow;
            int idx = arow * BK + ((kk * 32 + lko) ^ swr);
            af[m] = __builtin_bit_cast(f16x8, *reinterpret_cast<const uint4*>(&Ab[idx]));
        }
    };
    auto DEQB = [&](const uint32_t* Bpb, f16x8* b, int kk) {
        const int dcol = kk * 4 + (lane >> 4);
        const uint32_t MK = 0x000F000Fu, MG = 0x64006400u;
        #pragma unroll
        for (int n = 0; n < 4; ++n) {
            int brow = wc * 64 + n * 16 + lrow;
            uint32_t u = Bpb[brow * 8 + dcol];
            uint32_t p0 = (u & MK) | MG;
            uint32_t p1 = ((u >> 4) & MK) | MG;
            uint32_t p2 = ((u >> 8) & MK) | MG;
            uint32_t p3 = ((u >> 12) & MK) | MG;
            u32x4 o;
            o.x = __builtin_bit_cast(uint32_t, (__builtin_bit_cast(f16x2, p0) - zz[n]) * ss[n]);
            o.y = __builtin_bit_cast(uint32_t, (__builtin_bit_cast(f16x2, p1) - zz[n]) * ss[n]);
            o.z = __builtin_bit_cast(uint32_t, (__builtin_bit_cast(f16x2, p2) - zz[n]) * ss[n]);
            o.w = __builtin_bit_cast(uint32_t, (__builtin_bit_cast(f16x2, p3) - zz[n]) * ss[n]);
            b[n] = __builtin_bit_cast(f16x8, o);
        }
    };
    auto MFMAQ = [&](f16x8* bf, int mh) {
        #pragma unroll
        for (int m_ = 0; m_ < 4; ++m_)
            #pragma unroll
            for (int n_ = 0; n_ < 4; ++n_)
                acc[mh * 4 + m_][n_] = __builtin_amdgcn_mfma_f32_16x16x32_f16(
                    af[m_], bf[n_], acc[mh * 4 + m_][n_], 0, 0, 0);
    };

    PFG(0);
    GLDSB(0, Bp);
    LOADA(0);
    asm volatile("s_waitcnt vmcnt(0)" ::: "memory");
    #pragma unroll
    for (int c = 0; c < 4; ++c) WA(As, c);
    SETG(0);
    __syncthreads();

    for (int t = 0; t < NT; ++t) {
        const int grp = t >> 1;
        if (t && !(t & 1)) SETG(grp);
        if ((t & 1) && grp + 1 < ngrp) PFG(grp + 1);

        const int buf = t & 1;
        const unsigned short* Ab = As + buf * ASZ;
        const uint32_t* Bpb = Bp + buf * BPSZ;
        if (t + 1 < NT) {
            GLDSB((t + 1) * BK, Bp + (buf ^ 1) * BPSZ);
            LOADA((t + 1) * BK);
        }

        DEQB(Bpb, bfA, 0);
        RDA(Ab, 0, 0);
        MFMAQ(bfA, 0);
        RDA(Ab, 1, 0);
        MFMAQ(bfA, 1);
        DEQB(Bpb, bfB, 1);
        RDA(Ab, 0, 1);
        MFMAQ(bfB, 0);
        RDA(Ab, 1, 1);
        MFMAQ(bfB, 1);

        if (t + 1 < NT) { WA(As + (buf ^ 1) * ASZ, 0); WA(As + (buf ^ 1) * ASZ, 1);
                          WA(As + (buf ^ 1) * ASZ, 2); WA(As + (buf ^ 1) * ASZ, 3); }
        __syncthreads();
    }

    const int r4 = (lane >> 4) << 2;
    #pragma unroll
    for (int n = 0; n < 4; ++n) {
        int col = n0 + wc * 64 + n * 16 + lrow;
        float bv = bias[col];
        #pragma unroll
        for (int m = 0; m < 8; ++m) {
            size_t rbase = (size_t)(m0 + wr * 128 + m * 16 + r4) * N + col;
            #pragma unroll
            for (int e = 0; e < 4; ++e)
                __builtin_nontemporal_store(acc[m][n][e] + bv, &out[rbase + (size_t)e * N]);
        }
    }
}

extern "C" void kernel_launch(void* const* d_in, const int* in_sizes, int n_in,
                              void* d_out, int out_size, void* d_ws, size_t ws_size,
                              hipStream_t stream) {
    const float* x   = (const float*)d_in[0];
    const int*   qwp = (const int*)d_in[1];
    const int*   qzp = (const int*)d_in[2];
    const float* scp = (const float*)d_in[3];
    const float* bp  = (const float*)d_in[4];
    float* outp = (float*)d_out;

    const int N = in_sizes[4];                 // 4096 (O)
    const int K = (in_sizes[1] / N) * 8;       // 4096 (I)
    const int M = in_sizes[0] / K;             // 8192 (B)

    dim3 block(512);
    const size_t needX = (size_t)M * K * 2;
    const size_t needW = (size_t)N * K * 2;

    if (ws_size >= needX + needW) {
        unsigned short* xh  = (unsigned short*)d_ws;
        unsigned short* whf = xh + (size_t)M * K;
        int ncx = M * (K / 8), ncw = N * (K / 8);
        convert_x2_kernel<<<dim3((ncx + 255) / 256), dim3(256), 0, stream>>>(x, xh, M, K);
        convert_w3_kernel<<<dim3((ncw + 255) / 256), dim3(256), 0, stream>>>(qwp, qzp, scp, whf, N, K);
        dim3 grid2((M / 256) * (N / 256));     // 32*16 = 512
        const int ldsbytes = 4 * 256 * 32 * 2; // 64 KB (A only)
        (void)hipFuncSetAttribute(
            reinterpret_cast<const void*>(&awq_gemmbr_kernel),
            hipFuncAttributeMaxDynamicSharedMemorySize, ldsbytes);
        awq_gemmbr_kernel<<<grid2, block, ldsbytes, stream>>>(xh, whf, bp, outp, M, N, K);
    } else {
        dim3 grid((M / BM) * (N / BN));
        const int ldsbytes = 2 * BM * BK * 2 + 2 * BN * (BK / 8) * 4;
        (void)hipFuncSetAttribute(
            reinterpret_cast<const void*>(&awq_gemm0_kernel),
            hipFuncAttributeMaxDynamicSharedMemorySize, ldsbytes);
        awq_gemm0_kernel<<<grid, block, ldsbytes, stream>>>(
            x, qwp, qzp, scp, bp, outp, M, N, K);
    }
}

// Round 21
// 322.881 us; speedup vs baseline: 1.7572x; 1.0924x over previous
//
#include <hip/hip_runtime.h>
#include <stdint.h>

// AWQ 4-bit dequant GEMM: out[M,N] = x[M,K] @ W[N,K]^T + bias
// Path 2 (ws >= X+W): prepass x->fp16 and W->fp16 (dequant) into d_ws
//   (R12-verified layout: row-major [*][32]-subtiled, pair-permuted,
//   period-4 swizzle). GEMM: BM=BN=256, 512 thr (8 waves 2Mx4N, 128x64/wave).
//   2 PHASES per 64-k tile, phase = 32-k subtile kk:
//     {12 ds_read (af8+bf4, phase-local) | stage subtile kk of t+1 (4 glds)}
//     s_barrier; lgkmcnt(0); sched_barrier; setprio(1); 32 MFMA; setprio(0);
//     vmcnt(4) [FIFO: retires PREV phase's 4 stages = subtile read NEXT
//     phase; leaves this phase's 4]; s_barrier.   Tail phases: vmcnt(0).
//   Fixes R17's defects: no frags live across barriers (R17: af[8] cross-
//   barrier at 256-reg limit), 32-MFMA clusters (not 16), counted vmcnt per
//   phase (never drains in steady state). LDS 2buf x 2sub x (A+B) = 128 KB.
// Fallback: reg-staged fused kernel (no ws).

typedef _Float16 f16x2 __attribute__((ext_vector_type(2)));
typedef _Float16 f16x8 __attribute__((ext_vector_type(8)));
typedef float f32x4 __attribute__((ext_vector_type(4)));
typedef unsigned int u32x4 __attribute__((ext_vector_type(4)));

// ---------- prepass: x -> fp16 row-major, pair-perm, period-4 swizzle --------
__global__ void convert_x2_kernel(const float* __restrict__ x,
                                  unsigned short* __restrict__ xh,
                                  int M, int K) {
    int g = blockIdx.x * blockDim.x + threadIdx.x;
    int kc = K >> 3;
    if (g >= M * kc) return;
    int r  = g / kc;
    int cc = g - r * kc;
    int csrc = (cc & ~3) | ((cc & 3) ^ ((r >> 1) & 3));
    const float* p = x + (size_t)r * K + (csrc << 3);
    float4 f0 = *reinterpret_cast<const float4*>(p);
    float4 f1 = *reinterpret_cast<const float4*>(p + 4);
    u32x4 o;
    o.x = __builtin_bit_cast(uint32_t, __builtin_amdgcn_cvt_pkrtz(f0.x, f1.x));
    o.y = __builtin_bit_cast(uint32_t, __builtin_amdgcn_cvt_pkrtz(f0.y, f1.y));
    o.z = __builtin_bit_cast(uint32_t, __builtin_amdgcn_cvt_pkrtz(f0.z, f1.z));
    o.w = __builtin_bit_cast(uint32_t, __builtin_amdgcn_cvt_pkrtz(f0.w, f1.w));
    u32x4* dst = reinterpret_cast<u32x4*>(xh + (size_t)r * K + (cc << 3));
    __builtin_nontemporal_store(o, dst);
}

// ---------- prepass: W int4 -> fp16 dequant, same layout (R12-verified) ------
__global__ void convert_w2_kernel(const int* __restrict__ qw,
                                  const int* __restrict__ qz,
                                  const float* __restrict__ sc,
                                  unsigned short* __restrict__ wh,
                                  int Nrows, int K) {
    int g = blockIdx.x * blockDim.x + threadIdx.x;
    int kc = K >> 3;
    if (g >= Nrows * kc) return;
    int o  = g / kc;
    int cc = g - o * kc;
    int ngrp = K >> 7, nzw = ngrp >> 3;
    int grp = cc >> 4;
    float s = sc[(size_t)o * ngrp + grp];
    uint32_t z = ((uint32_t)qz[(size_t)o * nzw + (grp >> 3)] >> ((grp & 7) << 2)) & 0xF;
    uint32_t u = (uint32_t)qw[(size_t)o * kc + cc];
    _Float16 hs = (_Float16)s;
    _Float16 hz = (_Float16)(1024.0f + (float)z);   // integer <=1039: exact fp16
    f16x2 s2 = {hs, hs}, z2 = {hz, hz};
    const uint32_t MK = 0x000F000Fu, MG = 0x64006400u;
    uint32_t p0 = (u & MK) | MG;
    uint32_t p1 = ((u >> 4) & MK) | MG;
    uint32_t p2 = ((u >> 8) & MK) | MG;
    uint32_t p3 = ((u >> 12) & MK) | MG;
    u32x4 ov;
    ov.x = __builtin_bit_cast(uint32_t, (__builtin_bit_cast(f16x2, p0) - z2) * s2);
    ov.y = __builtin_bit_cast(uint32_t, (__builtin_bit_cast(f16x2, p1) - z2) * s2);
    ov.z = __builtin_bit_cast(uint32_t, (__builtin_bit_cast(f16x2, p2) - z2) * s2);
    ov.w = __builtin_bit_cast(uint32_t, (__builtin_bit_cast(f16x2, p3) - z2) * s2);
    int cdst = (cc & ~3) | ((cc & 3) ^ ((o >> 1) & 3));
    u32x4* dst = reinterpret_cast<u32x4*>(wh + (size_t)o * K + (cdst << 3));
    __builtin_nontemporal_store(ov, dst);
}

// ---------- path 2 GEMM: 2-phase/tile counted-vmcnt schedule -----------------
__global__ __launch_bounds__(512, 2) void awq_gemmph_kernel(
    const unsigned short* __restrict__ xh,
    const unsigned short* __restrict__ wh,
    const float* __restrict__ bias,
    float* __restrict__ out,
    int M, int N, int K)
{
    extern __shared__ __align__(16) unsigned short lds[];
    const int TSZ = 256 * 32;                 // 16 KB per subtile
    unsigned short* AB = lds;                 // A [2 buf][2 sub][TSZ]
    unsigned short* BB = lds + 4 * TSZ;       // B [2 buf][2 sub][TSZ]

    const int tid  = threadIdx.x;
    const int lane = tid & 63;
    const int wave = tid >> 6;
    const int wr   = wave >> 2;               // 0..1: 128-row half of A
    const int wc   = wave & 3;                // 0..3: 64-col quarter of B
    const int lrow = lane & 15;
    const int cswz = (((lane >> 4) ^ ((lrow >> 1) & 3)) << 3);

    const int cpx = gridDim.x >> 3;
    const int bid = (blockIdx.x & 7) * cpx + (blockIdx.x >> 3);
    const int ntn = N / 256;                  // 16
    const int m0 = (bid / ntn) * 256;
    const int n0 = (bid % ntn) * 256;
    const int NT = K >> 6;                    // 64 tiles of 64 k

    f32x4 acc[8][4];
    #pragma unroll
    for (int m = 0; m < 8; ++m)
        #pragma unroll
        for (int n = 0; n < 4; ++n)
            #pragma unroll
            for (int e = 0; e < 4; ++e) acc[m][n][e] = 0.f;

    // stage one 256x32 subtile: 2 glds per thread (R12/R18-verified map)
    auto GLDS = [&](const unsigned short* src, int row0, int kt, unsigned short* dst) {
        #pragma unroll
        for (int i = 0; i < 2; ++i) {
            int row = wave * 32 + i * 16 + (lane >> 2);
            const unsigned short* g = src + (size_t)(row0 + row) * K + kt + ((lane & 3) << 3);
            unsigned short* d = dst + row * 32 + ((lane & 3) << 3);
            __builtin_amdgcn_global_load_lds(
                (const __attribute__((address_space(1))) unsigned int*)g,
                (__attribute__((address_space(3))) unsigned int*)d, 16, 0, 0);
        }
    };
    // stage subtile `sub` of tile t into buf b: A + B (4 glds instr/wave)
    auto STAGE = [&](int t, int b, int sub) {
        GLDS(xh, m0, t * 64 + sub * 32, AB + (b * 2 + sub) * TSZ);
        GLDS(wh, n0, t * 64 + sub * 32, BB + (b * 2 + sub) * TSZ);
    };

    // one phase: frags + MFMA for subtile `sub` of buffer `buf`
    auto PHASE_COMPUTE = [&](int buf, int sub) {
        const unsigned short* Ab = AB + (buf * 2 + sub) * TSZ;
        const unsigned short* Bb = BB + (buf * 2 + sub) * TSZ;
        f16x8 bf[4], af[8];
        #pragma unroll
        for (int n = 0; n < 4; ++n) {
            int row = wc * 64 + n * 16 + lrow;
            bf[n] = __builtin_bit_cast(f16x8,
                    *reinterpret_cast<const uint4*>(&Bb[row * 32 + cswz]));
        }
        #pragma unroll
        for (int m = 0; m < 8; ++m) {
            int row = wr * 128 + m * 16 + lrow;
            af[m] = __builtin_bit_cast(f16x8,
                    *reinterpret_cast<const uint4*>(&Ab[row * 32 + cswz]));
        }
        __builtin_amdgcn_s_barrier();
        asm volatile("s_waitcnt lgkmcnt(0)" ::: "memory");
        __builtin_amdgcn_sched_barrier(0);
        __builtin_amdgcn_s_setprio(1);
        #pragma unroll
        for (int m = 0; m < 8; ++m)
            #pragma unroll
            for (int n = 0; n < 4; ++n)
                acc[m][n] = __builtin_amdgcn_mfma_f32_16x16x32_f16(
                    af[m], bf[n], acc[m][n], 0, 0, 0);
        __builtin_amdgcn_s_setprio(0);
    };

    // ---- prologue: stage both subtiles of tile 0; vmcnt(4); barrier
    STAGE(0, 0, 0);
    STAGE(0, 0, 1);
    asm volatile("s_waitcnt vmcnt(4)" ::: "memory");   // sub0 landed
    __builtin_amdgcn_s_barrier();

    for (int t = 0; t < NT; ++t) {
        const int buf = t & 1;
        const bool pf = (t + 1 < NT);

        // ---- phase 0 (subtile 0): reads sub0; stages sub0(t+1)
        if (pf) STAGE(t + 1, buf ^ 1, 0);
        PHASE_COMPUTE(buf, 0);
        // retire prev-phase stages (= sub1 of THIS tile, staged last phase of
        // t-1 / prologue) -> next phase's reads are safe. Leave this phase's 4.
        if (pf) { asm volatile("s_waitcnt vmcnt(4)" ::: "memory"); }
        else    { asm volatile("s_waitcnt vmcnt(0)" ::: "memory"); }
        __builtin_amdgcn_s_barrier();

        // ---- phase 1 (subtile 1): reads sub1; stages sub1(t+1)
        if (pf) STAGE(t + 1, buf ^ 1, 1);
        PHASE_COMPUTE(buf, 1);
        // retire phase-0's stages (= sub0 of t+1, read next phase)
        if (pf) { asm volatile("s_waitcnt vmcnt(4)" ::: "memory"); }
        else    { asm volatile("s_waitcnt vmcnt(0)" ::: "memory"); }
        __builtin_amdgcn_s_barrier();
    }

    // epilogue: C frag col=lane&15, row=(lane>>4)*4+e
    const int r4 = (lane >> 4) << 2;
    #pragma unroll
    for (int n = 0; n < 4; ++n) {
        int col = n0 + wc * 64 + n * 16 + lrow;
        float bv = bias[col];
        #pragma unroll
        for (int m = 0; m < 8; ++m) {
            size_t rbase = (size_t)(m0 + wr * 128 + m * 16 + r4) * N + col;
            #pragma unroll
            for (int e = 0; e < 4; ++e)
                __builtin_nontemporal_store(acc[m][n][e] + bv, &out[rbase + (size_t)e * N]);
        }
    }
}

// ================= fallback (ws too small): reg-staged fused ================
#define BM 256
#define BN 256
#define BK 64

__global__ __launch_bounds__(512, 2) void awq_gemm0_kernel(
    const float* __restrict__ x,
    const int*   __restrict__ qw,
    const int*   __restrict__ qz,
    const float* __restrict__ sc,
    const float* __restrict__ bias,
    float*       __restrict__ out,
    int M, int N, int K)
{
    extern __shared__ __align__(16) unsigned short lds[];
    const int ASZ  = BM * BK;
    const int BPSZ = BN * (BK / 8);
    unsigned short* As = lds;
    uint32_t* Bp = reinterpret_cast<uint32_t*>(lds + 2 * ASZ);

    const int tid  = threadIdx.x;
    const int lane = tid & 63;
    const int wave = tid >> 6;
    const int wr   = wave >> 2;
    const int wc   = wave & 3;
    const int lrow = lane & 15;
    const int lko  = (lane >> 4) << 3;
    const int swr  = (lrow & 7) << 3;

    const int cpx = gridDim.x >> 3;
    const int bid = (blockIdx.x & 7) * cpx + (blockIdx.x >> 3);
    const int ntn = N / BN;
    const int m0 = (bid / ntn) * BM;
    const int n0 = (bid % ntn) * BN;

    const int ngrp = K >> 7;
    const int nzw  = ngrp >> 3;
    const int kw   = K >> 3;
    const int NT   = K / BK;

    const int r_s = tid >> 1;
    const int kh  = tid & 1;
    const int sws = (r_s & 7) << 3;

    f32x4 acc[8][4];
    #pragma unroll
    for (int m = 0; m < 8; ++m)
        #pragma unroll
        for (int n = 0; n < 4; ++n)
            #pragma unroll
            for (int e = 0; e < 4; ++e) acc[m][n][e] = 0.f;

    float    sc_pf[4];
    uint32_t zq_pf[4];
    f16x2    ss[4], zz[4];
    auto PFG = [&](int grp) {
        #pragma unroll
        for (int n = 0; n < 4; ++n) {
            int og = n0 + wc * 64 + n * 16 + lrow;
            sc_pf[n] = sc[(size_t)og * ngrp + grp];
            zq_pf[n] = (uint32_t)qz[(size_t)og * nzw + (grp >> 3)];
        }
    };
    auto SETG = [&](int grp) {
        #pragma unroll
        for (int n = 0; n < 4; ++n) {
            _Float16 s = (_Float16)sc_pf[n];
            uint32_t z = (zq_pf[n] >> ((grp & 7) << 2)) & 0xF;
            _Float16 Z = (_Float16)(float)(1024u + z);
            ss[n][0] = s; ss[n][1] = s;
            zz[n][0] = Z; zz[n][1] = Z;
        }
    };

    float4 a32[8];

    auto GLDSB = [&](int kt, uint32_t* Bw) {
        int row = tid >> 1;
        const int* g = qw + (size_t)(n0 + row) * kw + (kt >> 3) + (tid & 1) * 4;
        uint32_t* d = Bw + row * 8 + (tid & 1) * 4;
        __builtin_amdgcn_global_load_lds(
            (const __attribute__((address_space(1))) unsigned int*)g,
            (__attribute__((address_space(3))) unsigned int*)d, 16, 0, 0);
    };
    auto LOADA = [&](int kt) {
        const float* p = x + (size_t)(m0 + r_s) * K + kt + kh * 32;
        #pragma unroll
        for (int i = 0; i < 8; ++i)
            a32[i] = *reinterpret_cast<const float4*>(p + 4 * i);
    };
    auto WA = [&](unsigned short* dst, int c) {
        uint4 o;
        o.x = __builtin_bit_cast(uint32_t, __builtin_amdgcn_cvt_pkrtz(a32[2*c].x, a32[2*c+1].x));
        o.y = __builtin_bit_cast(uint32_t, __builtin_amdgcn_cvt_pkrtz(a32[2*c].y, a32[2*c+1].y));
        o.z = __builtin_bit_cast(uint32_t, __builtin_amdgcn_cvt_pkrtz(a32[2*c].z, a32[2*c+1].z));
        o.w = __builtin_bit_cast(uint32_t, __builtin_amdgcn_cvt_pkrtz(a32[2*c].w, a32[2*c+1].w));
        int kcol = kh * 32 + 8 * c;
        *reinterpret_cast<uint4*>(&dst[r_s * BK + (kcol ^ sws)]) = o;
    };

    f16x8 af[4], bfA[4], bfB[4];
    auto RDA = [&](const unsigned short* Ab, int mh, int kk) {
        #pragma unroll
        for (int m = 0; m < 4; ++m) {
            int arow = wr * 128 + (mh * 4 + m) * 16 + lrow;
            int idx = arow * BK + ((kk * 32 + lko) ^ swr);
            af[m] = __builtin_bit_cast(f16x8, *reinterpret_cast<const uint4*>(&Ab[idx]));
        }
    };
    auto DEQB = [&](const uint32_t* Bpb, f16x8* b, int kk) {
        const int dcol = kk * 4 + (lane >> 4);
        const uint32_t MK = 0x000F000Fu, MG = 0x64006400u;
        #pragma unroll
        for (int n = 0; n < 4; ++n) {
            int brow = wc * 64 + n * 16 + lrow;
            uint32_t u = Bpb[brow * 8 + dcol];
            uint32_t p0 = (u & MK) | MG;
            uint32_t p1 = ((u >> 4) & MK) | MG;
            uint32_t p2 = ((u >> 8) & MK) | MG;
            uint32_t p3 = ((u >> 12) & MK) | MG;
            u32x4 o;
            o.x = __builtin_bit_cast(uint32_t, (__builtin_bit_cast(f16x2, p0) - zz[n]) * ss[n]);
            o.y = __builtin_bit_cast(uint32_t, (__builtin_bit_cast(f16x2, p1) - zz[n]) * ss[n]);
            o.z = __builtin_bit_cast(uint32_t, (__builtin_bit_cast(f16x2, p2) - zz[n]) * ss[n]);
            o.w = __builtin_bit_cast(uint32_t, (__builtin_bit_cast(f16x2, p3) - zz[n]) * ss[n]);
            b[n] = __builtin_bit_cast(f16x8, o);
        }
    };
    auto MFMAQ = [&](f16x8* bf, int mh) {
        #pragma unroll
        for (int m_ = 0; m_ < 4; ++m_)
            #pragma unroll
            for (int n_ = 0; n_ < 4; ++n_)
                acc[mh * 4 + m_][n_] = __builtin_amdgcn_mfma_f32_16x16x32_f16(
                    af[m_], bf[n_], acc[mh * 4 + m_][n_], 0, 0, 0);
    };

    PFG(0);
    GLDSB(0, Bp);
    LOADA(0);
    asm volatile("s_waitcnt vmcnt(0)" ::: "memory");
    #pragma unroll
    for (int c = 0; c < 4; ++c) WA(As, c);
    SETG(0);
    __syncthreads();

    for (int t = 0; t < NT; ++t) {
        const int grp = t >> 1;
        if (t && !(t & 1)) SETG(grp);
        if ((t & 1) && grp + 1 < ngrp) PFG(grp + 1);

        const int buf = t & 1;
        const unsigned short* Ab = As + buf * ASZ;
        const uint32_t* Bpb = Bp + buf * BPSZ;
        if (t + 1 < NT) {
            GLDSB((t + 1) * BK, Bp + (buf ^ 1) * BPSZ);
            LOADA((t + 1) * BK);
        }

        DEQB(Bpb, bfA, 0);
        RDA(Ab, 0, 0);
        MFMAQ(bfA, 0);
        RDA(Ab, 1, 0);
        MFMAQ(bfA, 1);
        DEQB(Bpb, bfB, 1);
        RDA(Ab, 0, 1);
        MFMAQ(bfB, 0);
        RDA(Ab, 1, 1);
        MFMAQ(bfB, 1);

        if (t + 1 < NT) { WA(As + (buf ^ 1) * ASZ, 0); WA(As + (buf ^ 1) * ASZ, 1);
                          WA(As + (buf ^ 1) * ASZ, 2); WA(As + (buf ^ 1) * ASZ, 3); }
        __syncthreads();
    }

    const int r4 = (lane >> 4) << 2;
    #pragma unroll
    for (int n = 0; n < 4; ++n) {
        int col = n0 + wc * 64 + n * 16 + lrow;
        float bv = bias[col];
        #pragma unroll
        for (int m = 0; m < 8; ++m) {
            size_t rbase = (size_t)(m0 + wr * 128 + m * 16 + r4) * N + col;
            #pragma unroll
            for (int e = 0; e < 4; ++e)
                __builtin_nontemporal_store(acc[m][n][e] + bv, &out[rbase + (size_t)e * N]);
        }
    }
}

extern "C" void kernel_launch(void* const* d_in, const int* in_sizes, int n_in,
                              void* d_out, int out_size, void* d_ws, size_t ws_size,
                              hipStream_t stream) {
    const float* x   = (const float*)d_in[0];
    const int*   qwp = (const int*)d_in[1];
    const int*   qzp = (const int*)d_in[2];
    const float* scp = (const float*)d_in[3];
    const float* bp  = (const float*)d_in[4];
    float* outp = (float*)d_out;

    const int N = in_sizes[4];                 // 4096 (O)
    const int K = (in_sizes[1] / N) * 8;       // 4096 (I)
    const int M = in_sizes[0] / K;             // 8192 (B)

    dim3 block(512);
    const size_t needX = (size_t)M * K * 2;
    const size_t needW = (size_t)N * K * 2;

    if (ws_size >= needX + needW) {
        unsigned short* xh = (unsigned short*)d_ws;
        unsigned short* wh = xh + (size_t)M * K;
        int ncx = M * (K / 8), ncw = N * (K / 8);
        convert_x2_kernel<<<dim3((ncx + 255) / 256), dim3(256), 0, stream>>>(x, xh, M, K);
        convert_w2_kernel<<<dim3((ncw + 255) / 256), dim3(256), 0, stream>>>(qwp, qzp, scp, wh, N, K);
        dim3 grid2((M / 256) * (N / 256));     // 512
        const int ldsbytes = 8 * 256 * 32 * 2; // 128 KB
        (void)hipFuncSetAttribute(
            reinterpret_cast<const void*>(&awq_gemmph_kernel),
            hipFuncAttributeMaxDynamicSharedMemorySize, ldsbytes);
        awq_gemmph_kernel<<<grid2, block, ldsbytes, stream>>>(xh, wh, bp, outp, M, N, K);
    } else {
        dim3 grid((M / BM) * (N / BN));
        const int ldsbytes = 2 * BM * BK * 2 + 2 * BN * (BK / 8) * 4;
        (void)hipFuncSetAttribute(
            reinterpret_cast<const void*>(&awq_gemm0_kernel),
            hipFuncAttributeMaxDynamicSharedMemorySize, ldsbytes);
        awq_gemm0_kernel<<<grid, block, ldsbytes, stream>>>(
            x, qwp, qzp, scp, bp, outp, M, N, K);
    }
}